// Round 6
// baseline (134.548 us; speedup 1.0000x reference)
//
#include <hip/hip_runtime.h>
#include <hip/hip_bf16.h>
#include <cstdint>

// ---------------- problem constants ----------------
#define BB 1024          // batch
#define DD 512           // dim
#define CC 50000         // classes
#define NTN 782          // ceil(50000/64) n-tiles
#define PSTRIDE 1564     // partials per row = NTN * 2 col-waves
#define NBLK 6256        // 8 m-tiles * 782 n-tiles (= 8*782, XCD-divisible)
#define SCALE_F 64.0f
#define COS_M_F 0.87758256189037276f
#define SIN_M_F 0.47942553860420301f
#define TH_F   (-0.87758256189037276f)
#define MM_F   0.23971276930210156f

#define LDSBUF 24576     // one buffer: A 16KB + B 8KB

typedef __attribute__((ext_vector_type(8))) short short8;
typedef __attribute__((ext_vector_type(8))) unsigned short ushort8;
typedef __attribute__((ext_vector_type(4))) float f32x4;

__device__ __forceinline__ unsigned short f2bf(float x) {
    union { __hip_bfloat16 h; unsigned short u; } v;
    v.h = __float2bfloat16(x);
    return v.u;
}

// ---------------- ws layout (bytes) ----------------
#define OFF_PS   ((size_t)0)                          // [1024][1564] float
#define OFF_LAB  (OFF_PS + (size_t)BB*PSTRIDE*4)      // [1024] float
#define OFF_NLL  (OFF_LAB + 4096)                     // [1024] float
#define OFF_E    (OFF_NLL + 4096)                     // [1024][512] bf16
#define OFF_WBF  (OFF_E + (size_t)BB*DD*2)            // [50000][512] bf16 normalized

// ---------------- kernel 1: normalize embeddings -> bf16 ----------------
__global__ void norm_e_kernel(const float* __restrict__ e, unsigned short* __restrict__ ebf) {
    const int b = blockIdx.x;          // 1024 blocks
    const int l = threadIdx.x;         // 64 threads
    const float4* row = reinterpret_cast<const float4*>(e + (size_t)b * DD);
    float4 v0 = row[l * 2 + 0];
    float4 v1 = row[l * 2 + 1];
    float s = v0.x*v0.x + v0.y*v0.y + v0.z*v0.z + v0.w*v0.w
            + v1.x*v1.x + v1.y*v1.y + v1.z*v1.z + v1.w*v1.w;
    #pragma unroll
    for (int m = 1; m < 64; m <<= 1) s += __shfl_xor(s, m);
    float inv = 1.0f / fmaxf(sqrtf(s), 1e-12f);
    ushort8 h;
    h[0]=f2bf(v0.x*inv); h[1]=f2bf(v0.y*inv); h[2]=f2bf(v0.z*inv); h[3]=f2bf(v0.w*inv);
    h[4]=f2bf(v1.x*inv); h[5]=f2bf(v1.y*inv); h[6]=f2bf(v1.z*inv); h[7]=f2bf(v1.w*inv);
    reinterpret_cast<ushort8*>(ebf + (size_t)b * DD)[l] = h;
}

// ---------------- kernel 2: normalize weights -> bf16 ----------------
__global__ void wnorm_bf16_kernel(const float* __restrict__ w, unsigned short* __restrict__ wbf) {
    const int row = blockIdx.x * 4 + (threadIdx.x >> 6);   // 12500 blocks * 4 waves
    const int l = threadIdx.x & 63;
    const float4* r = reinterpret_cast<const float4*>(w + (size_t)row * DD);
    float4 v0 = r[l * 2 + 0];
    float4 v1 = r[l * 2 + 1];
    float s = v0.x*v0.x + v0.y*v0.y + v0.z*v0.z + v0.w*v0.w
            + v1.x*v1.x + v1.y*v1.y + v1.z*v1.z + v1.w*v1.w;
    #pragma unroll
    for (int m = 1; m < 64; m <<= 1) s += __shfl_xor(s, m);
    float inv = 1.0f / fmaxf(sqrtf(s), 1e-12f);
    ushort8 h;
    h[0]=f2bf(v0.x*inv); h[1]=f2bf(v0.y*inv); h[2]=f2bf(v0.z*inv); h[3]=f2bf(v0.w*inv);
    h[4]=f2bf(v1.x*inv); h[5]=f2bf(v1.y*inv); h[6]=f2bf(v1.z*inv); h[7]=f2bf(v1.w*inv);
    reinterpret_cast<ushort8*>(wbf + (size_t)row * DD)[l] = h;
}

// ---------------- kernel 3: 128x64x64 GEMM + arcface + fixed-max lse ----
// 4 waves (2M x 2N); per-wave 64x32 output (4m x 2n frags of 16x16).
// DOUBLE-buffered LDS 48 KB, T3-minimal schedule with raw s_barrier:
//   per K-tile: issue STAGE(next) -> ds_read+MFMA(cur) -> vmcnt(0) -> s_barrier.
// One barrier per K-tile; stage latency hides under compute.
// 48 KB LDS -> 3 blocks/CU = 12 waves/CU.
__global__ __launch_bounds__(256, 3) void arc_gemm_kernel(
        const unsigned short* __restrict__ ebf,  // [1024][512] bf16 normalized
        const unsigned short* __restrict__ wbf,  // [50000][512] bf16 normalized
        const int* __restrict__ labels,          // [1024]
        float* __restrict__ part_s,              // [1024][1564]
        float* __restrict__ lab_logit)           // [1024]
{
    __shared__ __align__(16) char lds[2 * LDSBUF];

    const int t   = threadIdx.x;
    const int wv  = t >> 6;
    const int wr  = wv >> 1;           // row half 0..1 (64 rows)
    const int wc  = wv & 1;            // col half 0..1 (32 cols)
    const int l   = t & 63;
    const int r16 = l & 15;
    const int kg  = l >> 4;

    // XCD-bijective swizzle: 6256 = 8*782; m-tile fastest within an XCD chunk
    const int bid  = blockIdx.x;
    const int bidp = (bid & 7) * NTN + (bid >> 3);
    const int mt = bidp & 7;           // m-tile 0..7
    const int bn = bidp >> 3;          // n-tile 0..781
    const int m0 = mt * 128;
    const int c0 = bn * 64;

    f32x4 acc[4][2];
    #pragma unroll
    for (int m = 0; m < 4; ++m)
        #pragma unroll
        for (int n = 0; n < 2; ++n)
            acc[m][n] = (f32x4){0.f, 0.f, 0.f, 0.f};

    auto stage = [&](int base, int kt) {
        // A tile [128 rows][64 k] bf16, swizzled src
        #pragma unroll
        for (int i = 0; i < 4; ++i) {
            int flat = (i * 256 + t) * 16;
            int row  = flat >> 7;
            int scol = (flat & 127) ^ ((row & 7) << 4);
            const char* src = reinterpret_cast<const char*>(ebf)
                            + (size_t)(m0 + row) * (DD * 2) + kt * 128 + scol;
            __builtin_amdgcn_global_load_lds(
                (const __attribute__((address_space(1))) void*)src,
                (__attribute__((address_space(3))) void*)(&lds[base + flat]),
                16, 0, 0);
        }
        // B tile [64 classes][64 k] bf16
        #pragma unroll
        for (int i = 0; i < 2; ++i) {
            int flat = (i * 256 + t) * 16;
            int row  = flat >> 7;
            int scol = (flat & 127) ^ ((row & 7) << 4);
            int cls  = c0 + row;
            if (cls > CC - 1) cls = CC - 1;    // clamp; masked in epilogue
            const char* src = reinterpret_cast<const char*>(wbf)
                            + (size_t)cls * (DD * 2) + kt * 128 + scol;
            __builtin_amdgcn_global_load_lds(
                (const __attribute__((address_space(1))) void*)src,
                (__attribute__((address_space(3))) void*)(&lds[base + 16384 + flat]),
                16, 0, 0);
        }
    };

    auto compute = [&](int base) {
        #pragma unroll
        for (int kk = 0; kk < 2; ++kk) {
            const int kb = kk * 64 + kg * 16;
            short8 a[4], b[2];
            #pragma unroll
            for (int m = 0; m < 4; ++m) {
                int row = wr * 64 + m * 16 + r16;
                a[m] = *reinterpret_cast<const short8*>(&lds[base + row * 128 + (kb ^ ((row & 7) << 4))]);
            }
            #pragma unroll
            for (int n = 0; n < 2; ++n) {
                int row = wc * 32 + n * 16 + r16;
                b[n] = *reinterpret_cast<const short8*>(&lds[base + 16384 + row * 128 + (kb ^ ((row & 7) << 4))]);
            }
            #pragma unroll
            for (int m = 0; m < 4; ++m)
                #pragma unroll
                for (int n = 0; n < 2; ++n)
                    acc[m][n] = __builtin_amdgcn_mfma_f32_16x16x32_bf16(a[m], b[n], acc[m][n], 0, 0, 0);
        }
    };

    // ---- prologue: stage tile 0, drain, barrier ----
    stage(0, 0);
    asm volatile("s_waitcnt vmcnt(0)" ::: "memory");
    __builtin_amdgcn_s_barrier();

    // ---- pipelined K-loop: issue next stage, compute current, single barrier ----
    #pragma unroll
    for (int kt = 0; kt < 8; ++kt) {
        const int cur = (kt & 1) * LDSBUF;
        const int nxt = cur ^ LDSBUF;
        if (kt + 1 < 8) stage(nxt, kt + 1);
        compute(cur);
        asm volatile("s_waitcnt vmcnt(0)" ::: "memory");
        __builtin_amdgcn_s_barrier();
    }

    // ---- epilogue: fixed-max partial sum of exp(logit - 64) over this wave's 32 cols ----
    #pragma unroll
    for (int m = 0; m < 4; ++m) {
        #pragma unroll
        for (int j = 0; j < 4; ++j) {
            const int rl   = wr * 64 + m * 16 + kg * 4 + j;
            const int grow = m0 + rl;
            const int lab  = labels[grow];
            float s = 0.f;
            #pragma unroll
            for (int n = 0; n < 2; ++n) {
                float cosv = acc[m][n][j];
                int col = c0 + wc * 32 + n * 16 + r16;
                if (col < CC) {
                    float logit = SCALE_F * cosv;
                    if (col == lab) {
                        float c2 = fminf(fmaxf(cosv * cosv, 0.f), 1.f);
                        float phi = cosv * COS_M_F - sqrtf(1.f - c2) * SIN_M_F;
                        phi = (cosv > TH_F) ? phi : (cosv - MM_F);
                        logit = SCALE_F * phi;
                        lab_logit[grow] = logit;
                    }
                    s += __expf(logit - SCALE_F);   // logit <= 64 always
                }
            }
            #pragma unroll
            for (int mk = 1; mk < 16; mk <<= 1) s += __shfl_xor(s, mk);
            if (r16 == 0) {
                part_s[(size_t)grow * PSTRIDE + bn * 2 + wc] = s;
            }
        }
    }
}

// ---------------- kernel 4: per-row sum -> nll (fixed max = 64) ----------------
__global__ void row_lse_kernel(const float* __restrict__ part_s,
                               const float* __restrict__ lab_logit,
                               float* __restrict__ nll) {
    const int row = blockIdx.x;
    const int t = threadIdx.x;   // 256
    const float* ps = part_s + (size_t)row * PSTRIDE;
    float S = 0.f;
    for (int i = t; i < PSTRIDE; i += 256) S += ps[i];
    #pragma unroll
    for (int m = 1; m < 64; m <<= 1) S += __shfl_xor(S, m);
    __shared__ float reds[4];
    if ((t & 63) == 0) reds[t >> 6] = S;
    __syncthreads();
    if (t == 0) {
        float Sf = reds[0] + reds[1] + reds[2] + reds[3];
        // logsumexp = 64 + log(sum exp(l - 64)); nll = -(lab - lse)
        nll[row] = -(lab_logit[row] - SCALE_F - logf(Sf));
    }
}

// ---------------- kernel 5: mean over 1024 -> scalar ----------------
__global__ void mean_kernel(const float* __restrict__ nll, float* __restrict__ out) {
    const int t = threadIdx.x;  // 1024
    float v = nll[t];
    #pragma unroll
    for (int m = 1; m < 64; m <<= 1) v += __shfl_xor(v, m);
    __shared__ float red[16];
    if ((t & 63) == 0) red[t >> 6] = v;
    __syncthreads();
    if (t == 0) {
        float s = 0.f;
        #pragma unroll
        for (int i = 0; i < 16; ++i) s += red[i];
        out[0] = s * (1.0f / BB);
    }
}

// ---------------- launcher ----------------
extern "C" void kernel_launch(void* const* d_in, const int* in_sizes, int n_in,
                              void* d_out, int out_size, void* d_ws, size_t ws_size,
                              hipStream_t stream) {
    const float* emb    = (const float*)d_in[0];
    const int*   labels = (const int*)d_in[1];
    const float* wgt    = (const float*)d_in[2];
    float* out = (float*)d_out;
    char* ws = (char*)d_ws;

    float* ps     = (float*)(ws + OFF_PS);
    float* lablg  = (float*)(ws + OFF_LAB);
    float* nll    = (float*)(ws + OFF_NLL);
    unsigned short* ebf = (unsigned short*)(ws + OFF_E);
    unsigned short* wbf = (unsigned short*)(ws + OFF_WBF);

    norm_e_kernel<<<BB, 64, 0, stream>>>(emb, ebf);
    wnorm_bf16_kernel<<<CC / 4, 256, 0, stream>>>(wgt, wbf);
    arc_gemm_kernel<<<NBLK, 256, 0, stream>>>(ebf, wbf, labels, ps, lablg);
    row_lse_kernel<<<BB, 256, 0, stream>>>(ps, lablg, nll);
    mean_kernel<<<1, 1024, 0, stream>>>(nll, out);
}

// Round 7
// 115.971 us; speedup vs baseline: 1.1602x; 1.1602x over previous
//
#include <hip/hip_runtime.h>
#include <hip/hip_bf16.h>
#include <cstdint>

// ---------------- problem constants ----------------
#define BB 1024          // batch
#define DD 512           // dim
#define CC 50000         // classes
#define NTN 782          // ceil(50000/64) n-tiles (BN=64)
#define GROUPS 98        // n-tile groups per m-tile
#define NTPB 8           // n-tiles per block (last group: 6)
#define NBLK 784         // 8 m-tiles * 98 groups (= 8*98, XCD-divisible)
#define PSTRIDE 196      // partials per row = GROUPS * 2 col-wave-halves
#define SCALE_F 64.0f
#define COS_M_F 0.87758256189037276f
#define SIN_M_F 0.47942553860420301f
#define TH_F   (-0.87758256189037276f)
#define MM_F   0.23971276930210156f

typedef __attribute__((ext_vector_type(4))) int i32x4;
typedef __attribute__((ext_vector_type(8))) char char8;

// ---------------- ws layout (bytes) ----------------
#define OFF_PS   ((size_t)0)                          // [1024][196] float
#define OFF_LAB  (OFF_PS + (size_t)BB*PSTRIDE*4)      // [1024] float
#define OFF_NLL  (OFF_LAB + 4096)                     // [1024] float
#define OFF_ES   (OFF_NLL + 4096)                     // [1024] float (e scales)
#define OFF_WS   (OFF_ES + 4096)                      // [50000] float (w scales)
#define OFF_EI8  (OFF_WS + 204800)                    // [1024][512] i8
#define OFF_WI8  (OFF_EI8 + (size_t)BB*DD)            // [50000][512] i8

// ---------------- kernel 1: normalize+quantize embeddings -> i8 ----------------
__global__ void norm_e_i8_kernel(const float* __restrict__ e,
                                 char* __restrict__ ei8, float* __restrict__ es) {
    const int b = blockIdx.x;          // 1024 blocks
    const int l = threadIdx.x;         // 64 threads
    const float4* row = reinterpret_cast<const float4*>(e + (size_t)b * DD);
    float4 v0 = row[l * 2 + 0];
    float4 v1 = row[l * 2 + 1];
    float ss = v0.x*v0.x + v0.y*v0.y + v0.z*v0.z + v0.w*v0.w
             + v1.x*v1.x + v1.y*v1.y + v1.z*v1.z + v1.w*v1.w;
    float mx = fmaxf(fmaxf(fmaxf(fabsf(v0.x), fabsf(v0.y)), fmaxf(fabsf(v0.z), fabsf(v0.w))),
                     fmaxf(fmaxf(fabsf(v1.x), fabsf(v1.y)), fmaxf(fabsf(v1.z), fabsf(v1.w))));
    #pragma unroll
    for (int m = 1; m < 64; m <<= 1) {
        ss += __shfl_xor(ss, m);
        mx = fmaxf(mx, __shfl_xor(mx, m));
    }
    float nrm = fmaxf(sqrtf(ss), 1e-12f);
    float ma  = fmaxf(mx, 1e-20f);
    float qs  = 127.0f / ma;
    if (l == 0) es[b] = ma / (127.0f * nrm);
    char8 q;
    q[0]=(char)__float2int_rn(v0.x*qs); q[1]=(char)__float2int_rn(v0.y*qs);
    q[2]=(char)__float2int_rn(v0.z*qs); q[3]=(char)__float2int_rn(v0.w*qs);
    q[4]=(char)__float2int_rn(v1.x*qs); q[5]=(char)__float2int_rn(v1.y*qs);
    q[6]=(char)__float2int_rn(v1.z*qs); q[7]=(char)__float2int_rn(v1.w*qs);
    *reinterpret_cast<char8*>(ei8 + (size_t)b * DD + l * 8) = q;
}

// ---------------- kernel 2: normalize+quantize weights -> i8 ----------------
__global__ void wnorm_i8_kernel(const float* __restrict__ w,
                                char* __restrict__ wi8, float* __restrict__ wsc) {
    const int row = blockIdx.x * 4 + (threadIdx.x >> 6);   // 12500 blocks * 4 waves
    const int l = threadIdx.x & 63;
    const float4* r = reinterpret_cast<const float4*>(w + (size_t)row * DD);
    float4 v0 = r[l * 2 + 0];
    float4 v1 = r[l * 2 + 1];
    float ss = v0.x*v0.x + v0.y*v0.y + v0.z*v0.z + v0.w*v0.w
             + v1.x*v1.x + v1.y*v1.y + v1.z*v1.z + v1.w*v1.w;
    float mx = fmaxf(fmaxf(fmaxf(fabsf(v0.x), fabsf(v0.y)), fmaxf(fabsf(v0.z), fabsf(v0.w))),
                     fmaxf(fmaxf(fabsf(v1.x), fabsf(v1.y)), fmaxf(fabsf(v1.z), fabsf(v1.w))));
    #pragma unroll
    for (int m = 1; m < 64; m <<= 1) {
        ss += __shfl_xor(ss, m);
        mx = fmaxf(mx, __shfl_xor(mx, m));
    }
    float nrm = fmaxf(sqrtf(ss), 1e-12f);
    float ma  = fmaxf(mx, 1e-20f);
    float qs  = 127.0f / ma;
    if (l == 0) wsc[row] = ma / (127.0f * nrm);
    char8 q;
    q[0]=(char)__float2int_rn(v0.x*qs); q[1]=(char)__float2int_rn(v0.y*qs);
    q[2]=(char)__float2int_rn(v0.z*qs); q[3]=(char)__float2int_rn(v0.w*qs);
    q[4]=(char)__float2int_rn(v1.x*qs); q[5]=(char)__float2int_rn(v1.y*qs);
    q[6]=(char)__float2int_rn(v1.z*qs); q[7]=(char)__float2int_rn(v1.w*qs);
    *reinterpret_cast<char8*>(wi8 + (size_t)row * DD + l * 8) = q;
}

// ---------------- kernel 3: i8 GEMM, A-in-registers, persistent n-loop ----------
// Block: m-tile 128 rows (A frags in 128 VGPR, loaded once), loops over 8 n-tiles
// of 64 classes. B whole-K [64][512B] in LDS, double-buffered (64 KB -> 2 blk/CU).
// 4 waves 2M x 2N: per-wave 64 rows x 32 cols; per kk (K=64): 2 ds_read (B only),
// 8 x mfma_i32_16x16x64_i8. One barrier per n-tile. Sum-exp accumulated in regs
// across n-tiles; single shfl-reduce + part_s store per block.
__global__ __launch_bounds__(256, 2) void arc_gemm_i8_kernel(
        const char* __restrict__ ei8,    // [1024][512] i8
        const char* __restrict__ wi8,    // [50000][512] i8
        const float* __restrict__ es,    // [1024]
        const float* __restrict__ wsc,   // [50000]
        const int* __restrict__ labels,  // [1024]
        float* __restrict__ part_s,      // [1024][196]
        float* __restrict__ lab_logit)   // [1024]
{
    __shared__ __align__(16) char lds[2][32768];

    const int t   = threadIdx.x;
    const int wv  = t >> 6;
    const int wr  = wv >> 1;           // row half 0..1 (64 rows)
    const int wc  = wv & 1;            // col half 0..1 (32 cols)
    const int l   = t & 63;
    const int r16 = l & 15;
    const int kg  = l >> 4;

    // XCD-bijective: 784 = 8*98; within an XCD chunk m-tile varies fastest,
    // so the ~12 groups x 8 m-blocks on one XCD share B tiles in its L2.
    const int bid  = blockIdx.x;
    const int bidp = (bid & 7) * GROUPS + (bid >> 3);
    const int mt = bidp & 7;           // m-tile 0..7
    const int g  = bidp >> 3;          // group 0..97
    const int m0 = mt * 128;
    const int nt0 = g * NTPB;
    const int cnt = min(NTPB, NTN - nt0);

    // ---- A fragments: 4 m-frags x 8 kk, 16 B each -> 128 VGPR, from global ----
    i32x4 af[4][8];
    #pragma unroll
    for (int m = 0; m < 4; ++m)
        #pragma unroll
        for (int kk = 0; kk < 8; ++kk)
            af[m][kk] = *reinterpret_cast<const i32x4*>(
                ei8 + (size_t)(m0 + wr * 64 + m * 16 + r16) * DD + kk * 64 + kg * 16);

    // ---- per-row hoists: scale, label ----
    float se_r[4][4];
    int   lab_r[4][4];
    #pragma unroll
    for (int m = 0; m < 4; ++m)
        #pragma unroll
        for (int j = 0; j < 4; ++j) {
            int grow = m0 + wr * 64 + m * 16 + kg * 4 + j;
            se_r[m][j]  = es[grow];
            lab_r[m][j] = labels[grow];
        }

    float rs[4][4];
    #pragma unroll
    for (int m = 0; m < 4; ++m)
        #pragma unroll
        for (int j = 0; j < 4; ++j) rs[m][j] = 0.f;

    auto stageB = [&](int buf, int nt) {
        #pragma unroll
        for (int i = 0; i < 8; ++i) {
            int flat = (i * 256 + t) * 16;
            int row  = flat >> 9;                      // 0..63
            int scol = (flat & 511) ^ ((row & 7) << 4);
            int cls  = nt * 64 + row;
            if (cls > CC - 1) cls = CC - 1;            // clamp; masked below
            const char* src = wi8 + (size_t)cls * DD + scol;
            __builtin_amdgcn_global_load_lds(
                (const __attribute__((address_space(1))) void*)src,
                (__attribute__((address_space(3))) void*)(&lds[buf][flat]),
                16, 0, 0);
        }
    };

    // ---- prologue ----
    stageB(0, nt0);
    asm volatile("s_waitcnt vmcnt(0)" ::: "memory");
    __builtin_amdgcn_s_barrier();

    for (int i = 0; i < cnt; ++i) {
        const int buf = i & 1;
        if (i + 1 < cnt) stageB(buf ^ 1, nt0 + i + 1);

        // ---- compute: 8 kk, B from LDS, A from regs ----
        i32x4 acc[4][2];
        #pragma unroll
        for (int m = 0; m < 4; ++m)
            #pragma unroll
            for (int n = 0; n < 2; ++n) acc[m][n] = (i32x4){0, 0, 0, 0};
        #pragma unroll
        for (int kk = 0; kk < 8; ++kk) {
            i32x4 b[2];
            #pragma unroll
            for (int n = 0; n < 2; ++n) {
                int row = wc * 32 + n * 16 + r16;
                int off = row * 512 + ((kk * 64 + kg * 16) ^ ((row & 7) << 4));
                b[n] = *reinterpret_cast<const i32x4*>(&lds[buf][off]);
            }
            #pragma unroll
            for (int m = 0; m < 4; ++m)
                #pragma unroll
                for (int n = 0; n < 2; ++n)
                    acc[m][n] = __builtin_amdgcn_mfma_i32_16x16x64_i8(af[m][kk], b[n], acc[m][n], 0, 0, 0);
        }

        // ---- epilogue: accumulate exp(logit-64) into registers ----
        const int nt = nt0 + i;
        float swv[2];
        #pragma unroll
        for (int n = 0; n < 2; ++n) {
            int col = nt * 64 + wc * 32 + n * 16 + r16;
            swv[n] = wsc[col > CC - 1 ? CC - 1 : col];
        }
        #pragma unroll
        for (int m = 0; m < 4; ++m) {
            #pragma unroll
            for (int j = 0; j < 4; ++j) {
                const int lab = lab_r[m][j];
                #pragma unroll
                for (int n = 0; n < 2; ++n) {
                    int col = nt * 64 + wc * 32 + n * 16 + r16;
                    if (col < CC) {
                        float cosv = (float)acc[m][n][j] * se_r[m][j] * swv[n];
                        float logit = SCALE_F * cosv;
                        if (col == lab) {
                            float c2 = fminf(fmaxf(cosv * cosv, 0.f), 1.f);
                            float phi = cosv * COS_M_F - sqrtf(1.f - c2) * SIN_M_F;
                            phi = (cosv > TH_F) ? phi : (cosv - MM_F);
                            logit = SCALE_F * phi;
                            lab_logit[m0 + wr * 64 + m * 16 + kg * 4 + j] = logit;
                        }
                        rs[m][j] += __expf(logit - SCALE_F);
                    }
                }
            }
        }

        asm volatile("s_waitcnt vmcnt(0)" ::: "memory");
        __builtin_amdgcn_s_barrier();
    }

    // ---- block end: one shfl-reduce over r16, store partials ----
    #pragma unroll
    for (int m = 0; m < 4; ++m) {
        #pragma unroll
        for (int j = 0; j < 4; ++j) {
            float v = rs[m][j];
            #pragma unroll
            for (int mk = 1; mk < 16; mk <<= 1) v += __shfl_xor(v, mk);
            if (r16 == 0) {
                int grow = m0 + wr * 64 + m * 16 + kg * 4 + j;
                part_s[(size_t)grow * PSTRIDE + g * 2 + wc] = v;
            }
        }
    }
}

// ---------------- kernel 4: per-row sum -> nll (fixed max = 64) ----------------
__global__ void row_lse_kernel(const float* __restrict__ part_s,
                               const float* __restrict__ lab_logit,
                               float* __restrict__ nll) {
    const int row = blockIdx.x;
    const int t = threadIdx.x;   // 256
    const float* ps = part_s + (size_t)row * PSTRIDE;
    float S = 0.f;
    for (int i = t; i < PSTRIDE; i += 256) S += ps[i];
    #pragma unroll
    for (int m = 1; m < 64; m <<= 1) S += __shfl_xor(S, m);
    __shared__ float reds[4];
    if ((t & 63) == 0) reds[t >> 6] = S;
    __syncthreads();
    if (t == 0) {
        float Sf = reds[0] + reds[1] + reds[2] + reds[3];
        nll[row] = -(lab_logit[row] - SCALE_F - logf(Sf));
    }
}

// ---------------- kernel 5: mean over 1024 -> scalar ----------------
__global__ void mean_kernel(const float* __restrict__ nll, float* __restrict__ out) {
    const int t = threadIdx.x;  // 1024
    float v = nll[t];
    #pragma unroll
    for (int m = 1; m < 64; m <<= 1) v += __shfl_xor(v, m);
    __shared__ float red[16];
    if ((t & 63) == 0) red[t >> 6] = v;
    __syncthreads();
    if (t == 0) {
        float s = 0.f;
        #pragma unroll
        for (int i = 0; i < 16; ++i) s += red[i];
        out[0] = s * (1.0f / BB);
    }
}

// ---------------- launcher ----------------
extern "C" void kernel_launch(void* const* d_in, const int* in_sizes, int n_in,
                              void* d_out, int out_size, void* d_ws, size_t ws_size,
                              hipStream_t stream) {
    const float* emb    = (const float*)d_in[0];
    const int*   labels = (const int*)d_in[1];
    const float* wgt    = (const float*)d_in[2];
    float* out = (float*)d_out;
    char* ws = (char*)d_ws;

    float* ps     = (float*)(ws + OFF_PS);
    float* lablg  = (float*)(ws + OFF_LAB);
    float* nll    = (float*)(ws + OFF_NLL);
    float* es     = (float*)(ws + OFF_ES);
    float* wsc    = (float*)(ws + OFF_WS);
    char*  ei8    = (char*)(ws + OFF_EI8);
    char*  wi8    = (char*)(ws + OFF_WI8);

    norm_e_i8_kernel<<<BB, 64, 0, stream>>>(emb, ei8, es);
    wnorm_i8_kernel<<<CC / 4, 256, 0, stream>>>(wgt, wi8, wsc);
    arc_gemm_i8_kernel<<<NBLK, 256, 0, stream>>>(ei8, wi8, es, wsc, labels, ps, lablg);
    row_lse_kernel<<<BB, 256, 0, stream>>>(ps, lablg, nll);
    mean_kernel<<<1, 1024, 0, stream>>>(nll, out);
}

// Round 8
// 84.032 us; speedup vs baseline: 1.6011x; 1.3801x over previous
//
#include <hip/hip_runtime.h>
#include <hip/hip_bf16.h>
#include <cstdint>

// ---------------- problem constants ----------------
#define BB 1024          // batch
#define DD 512           // dim
#define CC 50000         // classes
#define NTN 782          // ceil(50000/64) n-tiles (BN=64)
#define GROUPS 98        // n-tile groups per m-tile (8 n-tiles each; last has 6)
#define NTPB 8
#define NBLK 784         // 8 m-tiles * 98 groups (= 8*98, XCD-divisible)
#define PSTRIDE 196      // partials per row = GROUPS * 2 col-wave-halves
#define SCALE_F 64.0f
#define COS_M_F 0.87758256189037276f
#define SIN_M_F 0.47942553860420301f
#define TH_F   (-0.87758256189037276f)
#define MM_F   0.23971276930210156f

typedef __attribute__((ext_vector_type(4))) int i32x4;
typedef __attribute__((ext_vector_type(8))) char char8;

// ---------------- ws layout (bytes) ----------------
#define OFF_PS   ((size_t)0)                          // [1024][196] float
#define OFF_LABV (OFF_PS + (size_t)BB*PSTRIDE*4)      // [1024][2] float {64*phi, adj}
#define OFF_NLL  (OFF_LABV + 8192)                    // [1024] float
#define OFF_ES   (OFF_NLL + 4096)                     // [1024] float (e scales)
#define OFF_WS   (OFF_ES + 4096)                      // [50000] float (w scales)
#define OFF_EI8  (OFF_WS + 204800)                    // [1024][512] i8
#define OFF_WI8  (OFF_EI8 + (size_t)BB*DD)            // [50000][512] i8

// ---------------- kernel 1: normalize+quantize embeddings -> i8 ----------------
__global__ void norm_e_i8_kernel(const float* __restrict__ e,
                                 char* __restrict__ ei8, float* __restrict__ es) {
    const int b = blockIdx.x;          // 1024 blocks
    const int l = threadIdx.x;         // 64 threads
    const float4* row = reinterpret_cast<const float4*>(e + (size_t)b * DD);
    float4 v0 = row[l * 2 + 0];
    float4 v1 = row[l * 2 + 1];
    float ss = v0.x*v0.x + v0.y*v0.y + v0.z*v0.z + v0.w*v0.w
             + v1.x*v1.x + v1.y*v1.y + v1.z*v1.z + v1.w*v1.w;
    float mx = fmaxf(fmaxf(fmaxf(fabsf(v0.x), fabsf(v0.y)), fmaxf(fabsf(v0.z), fabsf(v0.w))),
                     fmaxf(fmaxf(fabsf(v1.x), fabsf(v1.y)), fmaxf(fabsf(v1.z), fabsf(v1.w))));
    #pragma unroll
    for (int m = 1; m < 64; m <<= 1) {
        ss += __shfl_xor(ss, m);
        mx = fmaxf(mx, __shfl_xor(mx, m));
    }
    float nrm = fmaxf(sqrtf(ss), 1e-12f);
    float ma  = fmaxf(mx, 1e-20f);
    float qs  = 127.0f / ma;
    if (l == 0) es[b] = ma / (127.0f * nrm);
    char8 q;
    q[0]=(char)__float2int_rn(v0.x*qs); q[1]=(char)__float2int_rn(v0.y*qs);
    q[2]=(char)__float2int_rn(v0.z*qs); q[3]=(char)__float2int_rn(v0.w*qs);
    q[4]=(char)__float2int_rn(v1.x*qs); q[5]=(char)__float2int_rn(v1.y*qs);
    q[6]=(char)__float2int_rn(v1.z*qs); q[7]=(char)__float2int_rn(v1.w*qs);
    *reinterpret_cast<char8*>(ei8 + (size_t)b * DD + l * 8) = q;
}

// ---------------- kernel 2: normalize+quantize weights -> i8 ----------------
__global__ void wnorm_i8_kernel(const float* __restrict__ w,
                                char* __restrict__ wi8, float* __restrict__ wsc) {
    const int row = blockIdx.x * 4 + (threadIdx.x >> 6);   // 12500 blocks * 4 waves
    const int l = threadIdx.x & 63;
    const float4* r = reinterpret_cast<const float4*>(w + (size_t)row * DD);
    float4 v0 = r[l * 2 + 0];
    float4 v1 = r[l * 2 + 1];
    float ss = v0.x*v0.x + v0.y*v0.y + v0.z*v0.z + v0.w*v0.w
             + v1.x*v1.x + v1.y*v1.y + v1.z*v1.z + v1.w*v1.w;
    float mx = fmaxf(fmaxf(fmaxf(fabsf(v0.x), fabsf(v0.y)), fmaxf(fabsf(v0.z), fabsf(v0.w))),
                     fmaxf(fmaxf(fabsf(v1.x), fabsf(v1.y)), fmaxf(fabsf(v1.z), fabsf(v1.w))));
    #pragma unroll
    for (int m = 1; m < 64; m <<= 1) {
        ss += __shfl_xor(ss, m);
        mx = fmaxf(mx, __shfl_xor(mx, m));
    }
    float nrm = fmaxf(sqrtf(ss), 1e-12f);
    float ma  = fmaxf(mx, 1e-20f);
    float qs  = 127.0f / ma;
    if (l == 0) wsc[row] = ma / (127.0f * nrm);
    char8 q;
    q[0]=(char)__float2int_rn(v0.x*qs); q[1]=(char)__float2int_rn(v0.y*qs);
    q[2]=(char)__float2int_rn(v0.z*qs); q[3]=(char)__float2int_rn(v0.w*qs);
    q[4]=(char)__float2int_rn(v1.x*qs); q[5]=(char)__float2int_rn(v1.y*qs);
    q[6]=(char)__float2int_rn(v1.z*qs); q[7]=(char)__float2int_rn(v1.w*qs);
    *reinterpret_cast<char8*>(wi8 + (size_t)row * DD + l * 8) = q;
}

// ---------------- kernel 3: i8 GEMM, A-in-regs (64 VGPR), persistent n-loop ------
// 512 threads = 8 waves (4m x 2n); wave tile 32 rows x 32 cols (2m x 2n frags).
// A: af[2][8] = 64 VGPR, loaded once per block from L2-hot ei8.
// B: whole-K [4 kk2][64 rows][128 B] in LDS with per-128B XOR swizzle (round-5
// proven, 0 conflicts), double-buffered: 2 x 32 KB = 64 KB -> 2 blocks/CU.
// Per n-tile: stage next B (4 gload_lds/thread), 16 ds_read + 32 MFMA i8 /wave,
// branch-free epilogue accumulating exp(logit-64) in regs; 1 barrier per n-tile.
__global__ __launch_bounds__(512, 4) void arc_gemm_i8_kernel(
        const char* __restrict__ ei8,    // [1024][512] i8
        const char* __restrict__ wi8,    // [50000][512] i8
        const float* __restrict__ es,    // [1024]
        const float* __restrict__ wsc,   // [50000]
        float* __restrict__ part_s)      // [1024][196]
{
    __shared__ __align__(16) char lds[2][32768];

    const int t   = threadIdx.x;       // 0..511
    const int wid = t >> 6;
    const int wm  = wid >> 1;          // 0..3 (32-row chunk)
    const int wn  = wid & 1;           // 0..1 (32-col chunk)
    const int l   = t & 63;
    const int r16 = l & 15;
    const int kg  = l >> 4;

    // XCD-bijective: 784 = 8*98; m-tile fastest within an XCD chunk.
    const int bid  = blockIdx.x;
    const int bidp = (bid & 7) * GROUPS + (bid >> 3);
    const int mt = bidp & 7;           // m-tile 0..7
    const int g  = bidp >> 3;          // group 0..97
    const int m0 = mt * 128;
    const int nt0 = g * NTPB;
    const int cnt = min(NTPB, NTN - nt0);

    // ---- A fragments: 2 m-frags x 8 kk, 16 B each -> 64 VGPR ----
    i32x4 af[2][8];
    #pragma unroll
    for (int fm = 0; fm < 2; ++fm)
        #pragma unroll
        for (int kk = 0; kk < 8; ++kk)
            af[fm][kk] = *reinterpret_cast<const i32x4*>(
                ei8 + (size_t)(m0 + wm * 32 + fm * 16 + r16) * DD + kk * 64 + kg * 16);

    // ---- per-row e-scale hoist ----
    float se_r[2][4];
    #pragma unroll
    for (int fm = 0; fm < 2; ++fm)
        #pragma unroll
        for (int j = 0; j < 4; ++j)
            se_r[fm][j] = es[m0 + wm * 32 + fm * 16 + kg * 4 + j];

    float rs[2][4];
    #pragma unroll
    for (int fm = 0; fm < 2; ++fm)
        #pragma unroll
        for (int j = 0; j < 4; ++j) rs[fm][j] = 0.f;

    // ---- B staging: layout [kk2 0..3][row 0..63][128B], XOR swizzle per slice ----
    auto stageB = [&](int buf, int nt) {
        #pragma unroll
        for (int i = 0; i < 4; ++i) {
            int flat = (i * 512 + t) * 16;
            int kk2  = flat >> 13;                 // 0..3 (128B K-chunk)
            int row  = (flat >> 7) & 63;
            int col  = flat & 127;
            int scol = col ^ ((row & 7) << 4);
            int cls  = nt * 64 + row;
            if (cls > CC - 1) cls = CC - 1;        // clamp; masked in epilogue
            const char* src = wi8 + (size_t)cls * DD + kk2 * 128 + scol;
            __builtin_amdgcn_global_load_lds(
                (const __attribute__((address_space(1))) void*)src,
                (__attribute__((address_space(3))) void*)(&lds[buf][flat]),
                16, 0, 0);
        }
    };

    // ---- prologue ----
    stageB(0, nt0);
    asm volatile("s_waitcnt vmcnt(0)" ::: "memory");
    __builtin_amdgcn_s_barrier();

    for (int i = 0; i < cnt; ++i) {
        const int buf = i & 1;
        if (i + 1 < cnt) stageB(buf ^ 1, nt0 + i + 1);

        // ---- compute: 8 kk, B from LDS, A from regs ----
        i32x4 acc[2][2];
        #pragma unroll
        for (int fm = 0; fm < 2; ++fm)
            #pragma unroll
            for (int fn = 0; fn < 2; ++fn) acc[fm][fn] = (i32x4){0, 0, 0, 0};
        #pragma unroll
        for (int kk = 0; kk < 8; ++kk) {
            i32x4 b[2];
            #pragma unroll
            for (int fn = 0; fn < 2; ++fn) {
                int row = wn * 32 + fn * 16 + r16;
                int off = (kk >> 1) * 8192 + row * 128
                        + (((kk & 1) * 64 + kg * 16) ^ ((row & 7) << 4));
                b[fn] = *reinterpret_cast<const i32x4*>(&lds[buf][off]);
            }
            #pragma unroll
            for (int fm = 0; fm < 2; ++fm)
                #pragma unroll
                for (int fn = 0; fn < 2; ++fn)
                    acc[fm][fn] = __builtin_amdgcn_mfma_i32_16x16x64_i8(af[fm][kk], b[fn], acc[fm][fn], 0, 0, 0);
        }

        // ---- epilogue: branch-free accumulate exp(logit-64) ----
        const int nt = nt0 + i;
        #pragma unroll
        for (int fn = 0; fn < 2; ++fn) {
            int col = nt * 64 + wn * 32 + fn * 16 + r16;
            float sw = wsc[col > CC - 1 ? CC - 1 : col];
            bool ok = (col < CC);
            #pragma unroll
            for (int fm = 0; fm < 2; ++fm)
                #pragma unroll
                for (int j = 0; j < 4; ++j) {
                    float cosv = (float)acc[fm][fn][j] * se_r[fm][j] * sw;
                    float e = __expf(SCALE_F * cosv - SCALE_F);
                    rs[fm][j] += ok ? e : 0.f;
                }
        }

        asm volatile("s_waitcnt vmcnt(0)" ::: "memory");
        __builtin_amdgcn_s_barrier();
    }

    // ---- block end: shfl-reduce over r16, store partials ----
    #pragma unroll
    for (int fm = 0; fm < 2; ++fm) {
        #pragma unroll
        for (int j = 0; j < 4; ++j) {
            float v = rs[fm][j];
            #pragma unroll
            for (int mk = 1; mk < 16; mk <<= 1) v += __shfl_xor(v, mk);
            if (r16 == 0) {
                int grow = m0 + wm * 32 + fm * 16 + kg * 4 + j;
                part_s[(size_t)grow * PSTRIDE + g * 2 + wn] = v;
            }
        }
    }
}

// ---------------- kernel 3b: label-column fix (exact same quantized math) --------
__global__ void labfix_kernel(const char* __restrict__ ei8, const char* __restrict__ wi8,
                              const float* __restrict__ es, const float* __restrict__ wsc,
                              const int* __restrict__ labels, float* __restrict__ labv) {
    const int b = blockIdx.x;          // 1024 blocks
    const int l = threadIdx.x;         // 64 threads
    const int lab = labels[b];
    char8 a = *reinterpret_cast<const char8*>(ei8 + (size_t)b * DD + l * 8);
    char8 w = *reinterpret_cast<const char8*>(wi8 + (size_t)lab * DD + l * 8);
    int d = 0;
    #pragma unroll
    for (int k = 0; k < 8; ++k) d += (int)a[k] * (int)w[k];
    #pragma unroll
    for (int m = 1; m < 64; m <<= 1) d += __shfl_xor(d, m);
    if (l == 0) {
        float cosv = (float)d * es[b] * wsc[lab];          // same op order as GEMM
        float logit = SCALE_F * cosv;
        float sub = __expf(logit - SCALE_F);               // term GEMM added (unmargined)
        float c2 = fminf(fmaxf(cosv * cosv, 0.f), 1.f);
        float phi = cosv * COS_M_F - sqrtf(1.f - c2) * SIN_M_F;
        phi = (cosv > TH_F) ? phi : (cosv - MM_F);
        float ml = SCALE_F * phi;
        labv[2 * b]     = ml;                              // margined label logit
        labv[2 * b + 1] = __expf(ml - SCALE_F) - sub;      // net denominator adjustment
    }
}

// ---------------- kernel 4: per-row sum -> nll (fixed max = 64) ----------------
__global__ void row_lse_kernel(const float* __restrict__ part_s,
                               const float* __restrict__ labv,
                               float* __restrict__ nll) {
    const int row = blockIdx.x;
    const int t = threadIdx.x;   // 256
    const float* ps = part_s + (size_t)row * PSTRIDE;
    float S = 0.f;
    for (int i = t; i < PSTRIDE; i += 256) S += ps[i];
    #pragma unroll
    for (int m = 1; m < 64; m <<= 1) S += __shfl_xor(S, m);
    __shared__ float reds[4];
    if ((t & 63) == 0) reds[t >> 6] = S;
    __syncthreads();
    if (t == 0) {
        float Sf = reds[0] + reds[1] + reds[2] + reds[3] + labv[2 * row + 1];
        nll[row] = -(labv[2 * row] - SCALE_F - logf(Sf));
    }
}

// ---------------- kernel 5: mean over 1024 -> scalar ----------------
__global__ void mean_kernel(const float* __restrict__ nll, float* __restrict__ out) {
    const int t = threadIdx.x;  // 1024
    float v = nll[t];
    #pragma unroll
    for (int m = 1; m < 64; m <<= 1) v += __shfl_xor(v, m);
    __shared__ float red[16];
    if ((t & 63) == 0) red[t >> 6] = v;
    __syncthreads();
    if (t == 0) {
        float s = 0.f;
        #pragma unroll
        for (int i = 0; i < 16; ++i) s += red[i];
        out[0] = s * (1.0f / BB);
    }
}

// ---------------- launcher ----------------
extern "C" void kernel_launch(void* const* d_in, const int* in_sizes, int n_in,
                              void* d_out, int out_size, void* d_ws, size_t ws_size,
                              hipStream_t stream) {
    const float* emb    = (const float*)d_in[0];
    const int*   labels = (const int*)d_in[1];
    const float* wgt    = (const float*)d_in[2];
    float* out = (float*)d_out;
    char* ws = (char*)d_ws;

    float* ps     = (float*)(ws + OFF_PS);
    float* labv   = (float*)(ws + OFF_LABV);
    float* nll    = (float*)(ws + OFF_NLL);
    float* es     = (float*)(ws + OFF_ES);
    float* wsc    = (float*)(ws + OFF_WS);
    char*  ei8    = (char*)(ws + OFF_EI8);
    char*  wi8    = (char*)(ws + OFF_WI8);

    norm_e_i8_kernel<<<BB, 64, 0, stream>>>(emb, ei8, es);
    wnorm_i8_kernel<<<CC / 4, 256, 0, stream>>>(wgt, wi8, wsc);
    arc_gemm_i8_kernel<<<NBLK, 512, 0, stream>>>(ei8, wi8, es, wsc, ps);
    labfix_kernel<<<BB, 64, 0, stream>>>(ei8, wi8, es, wsc, labels, labv);
    row_lse_kernel<<<BB, 256, 0, stream>>>(ps, labv, nll);
    mean_kernel<<<1, 1024, 0, stream>>>(nll, out);
}

// Round 9
// 80.719 us; speedup vs baseline: 1.6669x; 1.0410x over previous
//
#include <hip/hip_runtime.h>
#include <hip/hip_bf16.h>
#include <cstdint>

// ---------------- problem constants ----------------
#define BB 1024          // batch
#define DD 512           // dim
#define CC 50000         // classes
#define NTN 782          // ceil(50000/64) n-tiles (BN=64)
#define NBLK 512         // 8 m-tiles * 64 n-splits = 2 blocks/CU exactly
#define SCALE_F 64.0f
#define COS_M_F 0.87758256189037276f
#define SIN_M_F 0.47942553860420301f
#define TH_F   (-0.87758256189037276f)
#define MM_F   0.23971276930210156f

typedef __attribute__((ext_vector_type(4))) int i32x4;
typedef __attribute__((ext_vector_type(8))) char char8;

// ---------------- ws layout (bytes) ----------------
#define OFF_RS   ((size_t)0)                          // [1024] float row sum-exp accum
#define OFF_ES   (OFF_RS + 4096)                      // [1024] float (e scales)
#define OFF_WS   (OFF_ES + 4096)                      // [50000] float (w scales)
#define OFF_EI8  (OFF_WS + 204800)                    // [1024][512] i8
#define OFF_WI8  (OFF_EI8 + (size_t)BB*DD)            // [50000][512] i8

// ---------------- kernel 1: fused normalize+quantize (W rows then E rows) -------
// blocks 0..12499: weight rows (4/block); 12500..12755: embedding rows (4/block);
// block 12756: zero rowsum + out.
__global__ void quant_kernel(const float* __restrict__ emb, const float* __restrict__ wgt,
                             char* __restrict__ ei8, float* __restrict__ es,
                             char* __restrict__ wi8, float* __restrict__ wsc,
                             float* __restrict__ rowsum, float* __restrict__ out) {
    const int blk = blockIdx.x;
    if (blk == 12756) {
        const int t = threadIdx.x;   // 256
        #pragma unroll
        for (int i = 0; i < 4; ++i) rowsum[i * 256 + t] = 0.f;
        if (t == 0) out[0] = 0.f;
        return;
    }
    const int r4 = threadIdx.x >> 6;
    const int l  = threadIdx.x & 63;
    const bool isw = blk < 12500;
    const int row = isw ? (blk * 4 + r4) : ((blk - 12500) * 4 + r4);
    const float* src = (isw ? wgt : emb) + (size_t)row * DD;
    const float4* r = reinterpret_cast<const float4*>(src);
    float4 v0 = r[l * 2 + 0];
    float4 v1 = r[l * 2 + 1];
    float ss = v0.x*v0.x + v0.y*v0.y + v0.z*v0.z + v0.w*v0.w
             + v1.x*v1.x + v1.y*v1.y + v1.z*v1.z + v1.w*v1.w;
    float mx = fmaxf(fmaxf(fmaxf(fabsf(v0.x), fabsf(v0.y)), fmaxf(fabsf(v0.z), fabsf(v0.w))),
                     fmaxf(fmaxf(fabsf(v1.x), fabsf(v1.y)), fmaxf(fabsf(v1.z), fabsf(v1.w))));
    #pragma unroll
    for (int m = 1; m < 64; m <<= 1) {
        ss += __shfl_xor(ss, m);
        mx = fmaxf(mx, __shfl_xor(mx, m));
    }
    float nrm = fmaxf(sqrtf(ss), 1e-12f);
    float ma  = fmaxf(mx, 1e-20f);
    float qs  = 127.0f / ma;
    if (l == 0) (isw ? wsc : es)[row] = ma / (127.0f * nrm);
    char8 q;
    q[0]=(char)__float2int_rn(v0.x*qs); q[1]=(char)__float2int_rn(v0.y*qs);
    q[2]=(char)__float2int_rn(v0.z*qs); q[3]=(char)__float2int_rn(v0.w*qs);
    q[4]=(char)__float2int_rn(v1.x*qs); q[5]=(char)__float2int_rn(v1.y*qs);
    q[6]=(char)__float2int_rn(v1.z*qs); q[7]=(char)__float2int_rn(v1.w*qs);
    *reinterpret_cast<char8*>((isw ? wi8 : ei8) + (size_t)row * DD + l * 8) = q;
}

// ---------------- kernel 2: i8 GEMM, A-in-regs, persistent n-loop, atomic out ----
// 512 blocks (8 m-tiles x 64 splits), 512 threads = 8 waves (4m x 2n);
// wave tile 32 rows x 32 cols. A: af[2][8]=64 VGPR loaded once. B: whole-K
// [4 kk2][64 rows][128B] LDS, per-128B XOR swizzle, double-buffered 64 KB.
// Splits: s<14 -> 13 n-tiles from 13s; s>=14 -> 12 n-tiles from 12s+14.
// Epilogue accumulates exp(logit-64) in regs; block end: shfl-reduce +
// one atomicAdd per row per wave into rowsum.
__global__ __launch_bounds__(512, 4) void arc_gemm_i8_kernel(
        const char* __restrict__ ei8,    // [1024][512] i8
        const char* __restrict__ wi8,    // [50000][512] i8
        const float* __restrict__ es,    // [1024]
        const float* __restrict__ wsc,   // [50000]
        float* __restrict__ rowsum)      // [1024]
{
    __shared__ __align__(16) char lds[2][32768];

    const int t   = threadIdx.x;       // 0..511
    const int wid = t >> 6;
    const int wm  = wid >> 1;          // 0..3 (32-row chunk)
    const int wn  = wid & 1;           // 0..1 (32-col chunk)
    const int l   = t & 63;
    const int r16 = l & 15;
    const int kg  = l >> 4;

    // XCD-bijective: 512 = 8*64; within an XCD chunk of 64 bidp, mt varies
    // fastest -> 8 m-tiles share each split's B range in that XCD's L2.
    const int bid  = blockIdx.x;
    const int bidp = (bid & 7) * 64 + (bid >> 3);
    const int mt = bidp & 7;           // m-tile 0..7
    const int s  = bidp >> 3;          // split 0..63
    const int m0 = mt * 128;
    const int nt0 = (s < 14) ? s * 13 : 12 * s + 14;
    const int cnt = (s < 14) ? 13 : 12;

    // ---- A fragments: 2 m-frags x 8 kk, 16 B each -> 64 VGPR ----
    i32x4 af[2][8];
    #pragma unroll
    for (int fm = 0; fm < 2; ++fm)
        #pragma unroll
        for (int kk = 0; kk < 8; ++kk)
            af[fm][kk] = *reinterpret_cast<const i32x4*>(
                ei8 + (size_t)(m0 + wm * 32 + fm * 16 + r16) * DD + kk * 64 + kg * 16);

    // ---- per-row e-scale hoist ----
    float se_r[2][4];
    #pragma unroll
    for (int fm = 0; fm < 2; ++fm)
        #pragma unroll
        for (int j = 0; j < 4; ++j)
            se_r[fm][j] = es[m0 + wm * 32 + fm * 16 + kg * 4 + j];

    float rs[2][4];
    #pragma unroll
    for (int fm = 0; fm < 2; ++fm)
        #pragma unroll
        for (int j = 0; j < 4; ++j) rs[fm][j] = 0.f;

    // ---- B staging: [kk2 0..3][row 0..63][128B], XOR swizzle per 128B slice ----
    auto stageB = [&](int buf, int nt) {
        #pragma unroll
        for (int i = 0; i < 4; ++i) {
            int flat = (i * 512 + t) * 16;
            int kk2  = flat >> 13;                 // 0..3 (128B K-chunk)
            int row  = (flat >> 7) & 63;
            int col  = flat & 127;
            int scol = col ^ ((row & 7) << 4);
            int cls  = nt * 64 + row;
            if (cls > CC - 1) cls = CC - 1;        // clamp; masked in epilogue
            const char* src = wi8 + (size_t)cls * DD + kk2 * 128 + scol;
            __builtin_amdgcn_global_load_lds(
                (const __attribute__((address_space(1))) void*)src,
                (__attribute__((address_space(3))) void*)(&lds[buf][flat]),
                16, 0, 0);
        }
    };

    // ---- prologue ----
    stageB(0, nt0);
    asm volatile("s_waitcnt vmcnt(0)" ::: "memory");
    __builtin_amdgcn_s_barrier();

    for (int i = 0; i < cnt; ++i) {
        const int buf = i & 1;
        if (i + 1 < cnt) stageB(buf ^ 1, nt0 + i + 1);

        // ---- compute: 8 kk, B from LDS, A from regs ----
        i32x4 acc[2][2];
        #pragma unroll
        for (int fm = 0; fm < 2; ++fm)
            #pragma unroll
            for (int fn = 0; fn < 2; ++fn) acc[fm][fn] = (i32x4){0, 0, 0, 0};
        #pragma unroll
        for (int kk = 0; kk < 8; ++kk) {
            i32x4 b[2];
            #pragma unroll
            for (int fn = 0; fn < 2; ++fn) {
                int row = wn * 32 + fn * 16 + r16;
                int off = (kk >> 1) * 8192 + row * 128
                        + (((kk & 1) * 64 + kg * 16) ^ ((row & 7) << 4));
                b[fn] = *reinterpret_cast<const i32x4*>(&lds[buf][off]);
            }
            #pragma unroll
            for (int fm = 0; fm < 2; ++fm)
                #pragma unroll
                for (int fn = 0; fn < 2; ++fn)
                    acc[fm][fn] = __builtin_amdgcn_mfma_i32_16x16x64_i8(af[fm][kk], b[fn], acc[fm][fn], 0, 0, 0);
        }

        // ---- epilogue: branch-free accumulate exp(logit-64) ----
        const int nt = nt0 + i;
        #pragma unroll
        for (int fn = 0; fn < 2; ++fn) {
            int col = nt * 64 + wn * 32 + fn * 16 + r16;
            float sw = wsc[col > CC - 1 ? CC - 1 : col];
            bool ok = (col < CC);
            #pragma unroll
            for (int fm = 0; fm < 2; ++fm)
                #pragma unroll
                for (int j = 0; j < 4; ++j) {
                    float cosv = (float)acc[fm][fn][j] * se_r[fm][j] * sw;
                    float e = __expf(SCALE_F * cosv - SCALE_F);
                    rs[fm][j] += ok ? e : 0.f;
                }
        }

        asm volatile("s_waitcnt vmcnt(0)" ::: "memory");
        __builtin_amdgcn_s_barrier();
    }

    // ---- block end: shfl-reduce over r16, one atomicAdd per row per wave ----
    #pragma unroll
    for (int fm = 0; fm < 2; ++fm) {
        #pragma unroll
        for (int j = 0; j < 4; ++j) {
            float v = rs[fm][j];
            #pragma unroll
            for (int mk = 1; mk < 16; mk <<= 1) v += __shfl_xor(v, mk);
            if (r16 == 0) {
                int grow = m0 + wm * 32 + fm * 16 + kg * 4 + j;
                atomicAdd(&rowsum[grow], v);
            }
        }
    }
}

// ---------------- kernel 3: finish = labfix + nll + mean (atomic) ----------------
__global__ void finish_kernel(const char* __restrict__ ei8, const char* __restrict__ wi8,
                              const float* __restrict__ es, const float* __restrict__ wsc,
                              const int* __restrict__ labels,
                              const float* __restrict__ rowsum, float* __restrict__ out) {
    const int b = blockIdx.x;          // 1024 blocks
    const int l = threadIdx.x;         // 64 threads
    const int lab = labels[b];
    char8 a = *reinterpret_cast<const char8*>(ei8 + (size_t)b * DD + l * 8);
    char8 w = *reinterpret_cast<const char8*>(wi8 + (size_t)lab * DD + l * 8);
    int d = 0;
    #pragma unroll
    for (int k = 0; k < 8; ++k) d += (int)a[k] * (int)w[k];
    #pragma unroll
    for (int m = 1; m < 64; m <<= 1) d += __shfl_xor(d, m);
    if (l == 0) {
        float cosv = (float)d * es[b] * wsc[lab];          // same op order as GEMM
        float logit = SCALE_F * cosv;
        float sub = __expf(logit - SCALE_F);               // unmargined term GEMM added
        float c2 = fminf(fmaxf(cosv * cosv, 0.f), 1.f);
        float phi = cosv * COS_M_F - sqrtf(1.f - c2) * SIN_M_F;
        phi = (cosv > TH_F) ? phi : (cosv - MM_F);
        float ml = SCALE_F * phi;
        float Sf = rowsum[b] + __expf(ml - SCALE_F) - sub;
        float nll = -(ml - SCALE_F - logf(Sf));
        atomicAdd(out, nll * (1.0f / BB));
    }
}

// ---------------- launcher ----------------
extern "C" void kernel_launch(void* const* d_in, const int* in_sizes, int n_in,
                              void* d_out, int out_size, void* d_ws, size_t ws_size,
                              hipStream_t stream) {
    const float* emb    = (const float*)d_in[0];
    const int*   labels = (const int*)d_in[1];
    const float* wgt    = (const float*)d_in[2];
    float* out = (float*)d_out;
    char* ws = (char*)d_ws;

    float* rowsum = (float*)(ws + OFF_RS);
    float* es     = (float*)(ws + OFF_ES);
    float* wsc    = (float*)(ws + OFF_WS);
    char*  ei8    = (char*)(ws + OFF_EI8);
    char*  wi8    = (char*)(ws + OFF_WI8);

    quant_kernel<<<12757, 256, 0, stream>>>(emb, wgt, ei8, es, wi8, wsc, rowsum, out);
    arc_gemm_i8_kernel<<<NBLK, 512, 0, stream>>>(ei8, wi8, es, wsc, rowsum);
    finish_kernel<<<BB, 64, 0, stream>>>(ei8, wi8, es, wsc, labels, rowsum, out);
}

// Round 10
// 76.459 us; speedup vs baseline: 1.7597x; 1.0557x over previous
//
#include <hip/hip_runtime.h>
#include <hip/hip_bf16.h>
#include <cstdint>

// ---------------- problem constants ----------------
#define BB 1024          // batch
#define DD 512           // dim
#define CC 50000         // classes
#define CCP 50048        // padded classes (782 * 64)
#define NTN 782          // n-tiles (BN=64)
#define NBLK 512         // 8 m-tiles * 64 n-splits = 2 blocks/CU exactly
#define SCALE_F 64.0f
#define COS_M_F 0.87758256189037276f
#define SIN_M_F 0.47942553860420301f
#define TH_F   (-0.87758256189037276f)
#define MM_F   0.23971276930210156f

typedef __attribute__((ext_vector_type(4))) int i32x4;
typedef __attribute__((ext_vector_type(8))) char char8;

// ---------------- ws layout (bytes) ----------------
#define OFF_RS   ((size_t)0)                          // [1024] float row sum-exp accum
#define OFF_ES   (OFF_RS + 4096)                      // [1024] float (e scales)
#define OFF_WS   (OFF_ES + 4096)                      // [50048] float (w scales, padded)
#define OFF_EI8  (OFF_WS + 204800)                    // [1024][512] i8
#define OFF_WI8  (OFF_EI8 + (size_t)BB*DD)            // [50048][512] i8 (padded)

// ---------------- kernel 1: fused normalize+quantize + init -------------------
// blocks 0..12499: weight rows (4/block); 12500..12755: embedding rows (4/block);
// block 12756: zero rowsum/out + zero W pad rows + wsc pad.
__global__ void quant_kernel(const float* __restrict__ emb, const float* __restrict__ wgt,
                             char* __restrict__ ei8, float* __restrict__ es,
                             char* __restrict__ wi8, float* __restrict__ wsc,
                             float* __restrict__ rowsum, float* __restrict__ out) {
    const int blk = blockIdx.x;
    if (blk == 12756) {
        const int t = threadIdx.x;   // 256
        #pragma unroll
        for (int i = 0; i < 4; ++i) rowsum[i * 256 + t] = 0.f;
        if (t == 0) out[0] = 0.f;
        // zero pad rows 50000..50047 (24576 B): 96 B per thread
        int4* pz = reinterpret_cast<int4*>(wi8 + (size_t)CC * DD + t * 96);
        #pragma unroll
        for (int i = 0; i < 6; ++i) pz[i] = (int4){0, 0, 0, 0};
        if (t < CCP - CC) wsc[CC + t] = 0.f;
        return;
    }
    const int r4 = threadIdx.x >> 6;
    const int l  = threadIdx.x & 63;
    const bool isw = blk < 12500;
    const int row = isw ? (blk * 4 + r4) : ((blk - 12500) * 4 + r4);
    const float* src = (isw ? wgt : emb) + (size_t)row * DD;
    const float4* r = reinterpret_cast<const float4*>(src);
    float4 v0 = r[l * 2 + 0];
    float4 v1 = r[l * 2 + 1];
    float ss = v0.x*v0.x + v0.y*v0.y + v0.z*v0.z + v0.w*v0.w
             + v1.x*v1.x + v1.y*v1.y + v1.z*v1.z + v1.w*v1.w;
    float mx = fmaxf(fmaxf(fmaxf(fabsf(v0.x), fabsf(v0.y)), fmaxf(fabsf(v0.z), fabsf(v0.w))),
                     fmaxf(fmaxf(fabsf(v1.x), fabsf(v1.y)), fmaxf(fabsf(v1.z), fabsf(v1.w))));
    #pragma unroll
    for (int m = 1; m < 64; m <<= 1) {
        ss += __shfl_xor(ss, m);
        mx = fmaxf(mx, __shfl_xor(mx, m));
    }
    float nrm = fmaxf(sqrtf(ss), 1e-12f);
    float ma  = fmaxf(mx, 1e-20f);
    float qs  = 127.0f / ma;
    if (l == 0) (isw ? wsc : es)[row] = ma / (127.0f * nrm);
    char8 q;
    q[0]=(char)__float2int_rn(v0.x*qs); q[1]=(char)__float2int_rn(v0.y*qs);
    q[2]=(char)__float2int_rn(v0.z*qs); q[3]=(char)__float2int_rn(v0.w*qs);
    q[4]=(char)__float2int_rn(v1.x*qs); q[5]=(char)__float2int_rn(v1.y*qs);
    q[6]=(char)__float2int_rn(v1.z*qs); q[7]=(char)__float2int_rn(v1.w*qs);
    *reinterpret_cast<char8*>((isw ? wi8 : ei8) + (size_t)row * DD + l * 8) = q;
}

// ---------------- kernel 2: i8 GEMM, A-in-regs, persistent n-loop, atomic out ----
// 512 blocks (8 m-tiles x 64 splits), 512 threads = 8 waves (4m x 2n);
// wave tile 32 rows x 32 cols. A: af[2][8]=64 VGPR loaded once. B: whole-K
// [4 kk2][64 rows][128B] LDS, per-128B XOR swizzle, double-buffered 64 KB.
// W padded to 50048 rows -> no clamps, branch-free epilogue with folded
// exp coefficient; stage pointers increment by constant 32 KB per round.
__global__ __launch_bounds__(512, 4) void arc_gemm_i8_kernel(
        const char* __restrict__ ei8,    // [1024][512] i8
        const char* __restrict__ wi8,    // [50048][512] i8 (padded)
        const float* __restrict__ es,    // [1024]
        const float* __restrict__ wsc,   // [50048] (padded)
        float* __restrict__ rowsum)      // [1024]
{
    __shared__ __align__(16) char lds[2][32768];

    const int t   = threadIdx.x;       // 0..511
    const int wid = t >> 6;
    const int wm  = wid >> 1;          // 0..3 (32-row chunk)
    const int wn  = wid & 1;           // 0..1 (32-col chunk)
    const int l   = t & 63;
    const int r16 = l & 15;
    const int kg  = l >> 4;

    // XCD-bijective: XCD k gets splits [8k,8k+8) x all 8 m-tiles.
    const int bid  = blockIdx.x;
    const int bidp = (bid & 7) * 64 + (bid >> 3);
    const int mt = bidp & 7;           // m-tile 0..7
    const int s  = bidp >> 3;          // split 0..63
    const int m0 = mt * 128;
    const int nt0 = (s < 14) ? s * 13 : 12 * s + 14;
    const int cnt = (s < 14) ? 13 : 12;

    // ---- A fragments: 2 m-frags x 8 kk, 16 B each -> 64 VGPR ----
    i32x4 af[2][8];
    #pragma unroll
    for (int fm = 0; fm < 2; ++fm)
        #pragma unroll
        for (int kk = 0; kk < 8; ++kk)
            af[fm][kk] = *reinterpret_cast<const i32x4*>(
                ei8 + (size_t)(m0 + wm * 32 + fm * 16 + r16) * DD + kk * 64 + kg * 16);

    // ---- per-row e-scale hoist ----
    float se_r[2][4];
    #pragma unroll
    for (int fm = 0; fm < 2; ++fm)
        #pragma unroll
        for (int j = 0; j < 4; ++j)
            se_r[fm][j] = es[m0 + wm * 32 + fm * 16 + kg * 4 + j];

    float rs[2][4];
    #pragma unroll
    for (int fm = 0; fm < 2; ++fm)
        #pragma unroll
        for (int j = 0; j < 4; ++j) rs[fm][j] = 0.f;

    // ---- persistent stage pointers (stride 64 rows * 512 B = 32768 B/round) ----
    const char* sp[4];
    #pragma unroll
    for (int i = 0; i < 4; ++i) {
        int flat = (i * 512 + t) * 16;
        int kk2  = flat >> 13;
        int row  = (flat >> 7) & 63;
        int col  = flat & 127;
        int scol = col ^ ((row & 7) << 4);
        sp[i] = wi8 + (size_t)(nt0 * 64 + row) * DD + kk2 * 128 + scol;
    }
    auto stageB = [&](int buf) {
        #pragma unroll
        for (int i = 0; i < 4; ++i) {
            __builtin_amdgcn_global_load_lds(
                (const __attribute__((address_space(1))) void*)sp[i],
                (__attribute__((address_space(3))) void*)(&lds[buf][(i * 512 + t) * 16]),
                16, 0, 0);
            sp[i] += 64 * DD;
        }
    };
    // w-scale pointer for this thread's two columns (stride 64 floats/round)
    const float* wp = wsc + nt0 * 64 + wn * 32 + r16;

    // ---- prologue ----
    stageB(0);
    asm volatile("s_waitcnt vmcnt(0)" ::: "memory");
    __builtin_amdgcn_s_barrier();

    for (int i = 0; i < cnt; ++i) {
        const int buf = i & 1;
        if (i + 1 < cnt) stageB(buf ^ 1);

        // hoisted: per-col folded coefficients (latency hidden under MFMA)
        float sw64_0 = wp[0]  * SCALE_F;
        float sw64_1 = wp[16] * SCALE_F;
        wp += 64;

        // ---- compute: 8 kk, B from LDS, A from regs ----
        i32x4 acc[2][2];
        #pragma unroll
        for (int fm = 0; fm < 2; ++fm)
            #pragma unroll
            for (int fn = 0; fn < 2; ++fn) acc[fm][fn] = (i32x4){0, 0, 0, 0};
        #pragma unroll
        for (int kk = 0; kk < 8; ++kk) {
            i32x4 b[2];
            #pragma unroll
            for (int fn = 0; fn < 2; ++fn) {
                int row = wn * 32 + fn * 16 + r16;
                int off = (kk >> 1) * 8192 + row * 128
                        + (((kk & 1) * 64 + kg * 16) ^ ((row & 7) << 4));
                b[fn] = *reinterpret_cast<const i32x4*>(&lds[buf][off]);
            }
            #pragma unroll
            for (int fm = 0; fm < 2; ++fm)
                #pragma unroll
                for (int fn = 0; fn < 2; ++fn)
                    acc[fm][fn] = __builtin_amdgcn_mfma_i32_16x16x64_i8(af[fm][kk], b[fn], acc[fm][fn], 0, 0, 0);
        }

        // ---- epilogue: rs += exp(fma(d, se*sw*64, -64)), branch-free ----
        #pragma unroll
        for (int fm = 0; fm < 2; ++fm)
            #pragma unroll
            for (int j = 0; j < 4; ++j) {
                float k0 = se_r[fm][j] * sw64_0;
                float k1 = se_r[fm][j] * sw64_1;
                rs[fm][j] += __expf(fmaf((float)acc[fm][0][j], k0, -SCALE_F));
                rs[fm][j] += __expf(fmaf((float)acc[fm][1][j], k1, -SCALE_F));
            }

        asm volatile("s_waitcnt vmcnt(0)" ::: "memory");
        __builtin_amdgcn_s_barrier();
    }

    // ---- block end: shfl-reduce over r16, one atomicAdd per row per wave ----
    #pragma unroll
    for (int fm = 0; fm < 2; ++fm) {
        #pragma unroll
        for (int j = 0; j < 4; ++j) {
            float v = rs[fm][j];
            #pragma unroll
            for (int mk = 1; mk < 16; mk <<= 1) v += __shfl_xor(v, mk);
            if (r16 == 0) {
                int grow = m0 + wm * 32 + fm * 16 + kg * 4 + j;
                atomicAdd(&rowsum[grow], v);
            }
        }
    }
}

// ---------------- kernel 3: finish = labfix + nll + mean (atomic) ----------------
__global__ void finish_kernel(const char* __restrict__ ei8, const char* __restrict__ wi8,
                              const float* __restrict__ es, const float* __restrict__ wsc,
                              const int* __restrict__ labels,
                              const float* __restrict__ rowsum, float* __restrict__ out) {
    const int b = blockIdx.x;          // 1024 blocks
    const int l = threadIdx.x;         // 64 threads
    const int lab = labels[b];
    char8 a = *reinterpret_cast<const char8*>(ei8 + (size_t)b * DD + l * 8);
    char8 w = *reinterpret_cast<const char8*>(wi8 + (size_t)lab * DD + l * 8);
    int d = 0;
    #pragma unroll
    for (int k = 0; k < 8; ++k) d += (int)a[k] * (int)w[k];
    #pragma unroll
    for (int m = 1; m < 64; m <<= 1) d += __shfl_xor(d, m);
    if (l == 0) {
        // bit-match the GEMM's unmargined term: exp(fma(d, es*(wsc*64), -64))
        float kf  = es[b] * (wsc[lab] * SCALE_F);
        float sub = __expf(fmaf((float)d, kf, -SCALE_F));
        float cosv = (float)d * es[b] * wsc[lab];
        float c2 = fminf(fmaxf(cosv * cosv, 0.f), 1.f);
        float phi = cosv * COS_M_F - sqrtf(1.f - c2) * SIN_M_F;
        phi = (cosv > TH_F) ? phi : (cosv - MM_F);
        float ml = SCALE_F * phi;
        float Sf = rowsum[b] + __expf(ml - SCALE_F) - sub;
        float nll = -(ml - SCALE_F - logf(Sf));
        atomicAdd(out, nll * (1.0f / BB));
    }
}

// ---------------- launcher ----------------
extern "C" void kernel_launch(void* const* d_in, const int* in_sizes, int n_in,
                              void* d_out, int out_size, void* d_ws, size_t ws_size,
                              hipStream_t stream) {
    const float* emb    = (const float*)d_in[0];
    const int*   labels = (const int*)d_in[1];
    const float* wgt    = (const float*)d_in[2];
    float* out = (float*)d_out;
    char* ws = (char*)d_ws;

    float* rowsum = (float*)(ws + OFF_RS);
    float* es     = (float*)(ws + OFF_ES);
    float* wsc    = (float*)(ws + OFF_WS);
    char*  ei8    = (char*)(ws + OFF_EI8);
    char*  wi8    = (char*)(ws + OFF_WI8);

    quant_kernel<<<12757, 256, 0, stream>>>(emb, wgt, ei8, es, wi8, wsc, rowsum, out);
    arc_gemm_i8_kernel<<<NBLK, 512, 0, stream>>>(ei8, wi8, es, wsc, rowsum);
    finish_kernel<<<BB, 64, 0, stream>>>(ei8, wi8, es, wsc, labels, rowsum, out);
}